// Round 8
// baseline (112.410 us; speedup 1.0000x reference)
//
#include <hip/hip_runtime.h>
#include <math.h>

#define B_TOT 2048
#define R_TOT 512
#define D_TOT 256
#define LOG2E 1.4426950408889634f
#define SCALE_C 2.220446049250313e-16f   // 2^-52 exact

typedef float vf4 __attribute__((ext_vector_type(4)));
typedef float vf2 __attribute__((ext_vector_type(2)));

// ---- forced packed-f32 math (VOP3P). Per-half semantics identical to the
// scalar ops the compiler would emit -> bit-identical results. If LLVM was
// already forming pk ops these are the same instructions (cost-neutral);
// if it was scalarizing (suspected from busy-cycle fit), this halves the
// VALU issue cost of every vf4 stage.
static __device__ __forceinline__ vf2 pk_fma(vf2 a, vf2 b, vf2 c) {
    vf2 d;
    asm("v_pk_fma_f32 %0, %1, %2, %3" : "=v"(d) : "v"(a), "v"(b), "v"(c));
    return d;
}
static __device__ __forceinline__ vf2 pk_mul(vf2 a, vf2 b) {
    vf2 d;
    asm("v_pk_mul_f32 %0, %1, %2" : "=v"(d) : "v"(a), "v"(b));
    return d;
}
static __device__ __forceinline__ vf2 pk_add(vf2 a, vf2 b) {
    vf2 d;
    asm("v_pk_add_f32 %0, %1, %2" : "=v"(d) : "v"(a), "v"(b));
    return d;
}
static __device__ __forceinline__ vf4 pk4_fma(vf4 a, vf4 b, vf4 c) {
    vf4 d; d.lo = pk_fma(a.lo, b.lo, c.lo); d.hi = pk_fma(a.hi, b.hi, c.hi);
    return d;
}
static __device__ __forceinline__ vf4 pk4_mul(vf4 a, vf4 b) {
    vf4 d; d.lo = pk_mul(a.lo, b.lo); d.hi = pk_mul(a.hi, b.hi);
    return d;
}
static __device__ __forceinline__ vf4 pk4_add(vf4 a, vf4 b) {
    vf4 d; d.lo = pk_add(a.lo, b.lo); d.hi = pk_add(a.hi, b.hi);
    return d;
}

// gated = (1 + m1*e)/(1 + e),  e = exp2(A*x + Bc)
// A = -log2e*kappa*tanh(sign), Bc = -A*th, m1 = 1 - sigmoid(mask)
// Param planes: ppA[r*256+d], ppB[r*256+d], ppM[r*256+d].
// ppM carries 2^-52 folded at d%8==0 so each 8-d rcp group's num/den both
// carry the same scale -> ratio exact.
// Also zeroes y (blocks 0..7) so the separate memset dispatch is dropped.

__global__ void prep_kernel(const float* __restrict__ th,
                            const float* __restrict__ sp,
                            const float* __restrict__ ml,
                            const float* __restrict__ lk,
                            float* __restrict__ pp,
                            float* __restrict__ y) {
    int idx = blockIdx.x * 256 + threadIdx.x;   // r*256 + d
    if (blockIdx.x < (B_TOT / 256)) y[idx] = 0.0f;   // idx < 2048 here
    if (idx >= R_TOT * D_TOT) return;
    float kmul = -LOG2E * __builtin_amdgcn_exp2f(lk[0] * LOG2E);
    float u  = sp[idx];
    float eu = __builtin_amdgcn_exp2f(2.0f * LOG2E * u);
    float t  = 1.0f - 2.0f * __builtin_amdgcn_rcpf(eu + 1.0f);
    float A  = kmul * t;
    float Bc = -A * th[idx];
    float em = __builtin_amdgcn_exp2f(LOG2E * ml[idx]);
    float m1 = __builtin_amdgcn_rcpf(1.0f + em);
    int d = idx & 255;
    pp[idx]                       = A;
    pp[R_TOT * D_TOT + idx]       = Bc;
    pp[2 * R_TOT * D_TOT + idx]   = m1 * (((d & 7) == 0) ? SCALE_C : 1.0f);
}

// ---------------------------------------------------------------------------
// Main: WG = 512 = 8 waves. wave -> 1 rule (straight-line, fully unrolled —
// round-5's dynamic rule loop spilled to scratch, 60x HBM traffic, NEVER
// again); WG -> 8 rules x 64 batches (r8: doubled from 32 to amortize the
// param prologue + end-phase ramp over 16 q-iters). Lane l owns the FULL
// 8-d group d = 8*(l&31)..+7; lane halves (p = l>>5) cover two batch rows
// per step. In-lane 8-way num/den product trees via forced v_pk ops, one
// rcp per 2 batches. One atomicAdd per (block, batch): 64 adds/address.
// LDS 75.8 KB -> 2 blocks/CU x 512 thr = 4 waves/SIMD (r1: >=2.8 suffices).
// grid = (512/8 rules, 2048/64 batches) = 64 x 32.
// ---------------------------------------------------------------------------
__global__ __launch_bounds__(512, 4) void main_kernel(
        const float* __restrict__ x,       // [B_TOT][D_TOT]
        const float* __restrict__ pp,      // 3 planes of [R_TOT][D_TOT]
        const float* __restrict__ head_w,  // [R_TOT]
        const float* __restrict__ head_b,  // [1]
        float*       __restrict__ y) {     // [B_TOT]
    __shared__ float rbuf[8][64][36];      // 73.7 KB; pad 36: 16B-aligned
    __shared__ float wz[8][64];

    const int tid  = threadIdx.x;
    const int lane = tid & 63;
    const int wave = tid >> 6;             // 0..7
    const int col  = lane & 31;            // which 8-d group
    const int p    = lane >> 5;            // batch parity within row pair
    const int r0   = (blockIdx.x << 3) + wave;   // this wave's rule
    const int b0   = blockIdx.y << 6;            // 64 batches

    // ---- params: 8 d's per lane = two vf4 per plane, held in VGPRs ----
    const float* ppr = pp + r0 * D_TOT + (col << 3);
    vf4 A0  = *(const vf4*)(ppr);
    vf4 A1  = *(const vf4*)(ppr + 4);
    vf4 Bc0 = *(const vf4*)(ppr + R_TOT * D_TOT);
    vf4 Bc1 = *(const vf4*)(ppr + R_TOT * D_TOT + 4);
    vf4 M0  = *(const vf4*)(ppr + 2 * R_TOT * D_TOT);     // .x carries 2^-52
    vf4 M1  = *(const vf4*)(ppr + 2 * R_TOT * D_TOT + 4);
    const vf4 Klo = {SCALE_C, 1.0f, 1.0f, 1.0f};
    const vf4 One = {1.0f, 1.0f, 1.0f, 1.0f};

    const float* xb = x + (size_t)(b0 + p) * D_TOT + (col << 3);

    #pragma unroll
    for (int q = 0; q < 16; q++) {
        // batch rows 4q+p ("A") and 4q+2+p ("C")
        const float* xq = xb + q * (4 * D_TOT);
        vf4 xa0 = *(const vf4*)(xq);
        vf4 xa1 = *(const vf4*)(xq + 4);
        vf4 xc0 = *(const vf4*)(xq + 2 * D_TOT);
        vf4 xc1 = *(const vf4*)(xq + 2 * D_TOT + 4);

        vf4 ta0 = pk4_fma(A0, xa0, Bc0);
        vf4 ta1 = pk4_fma(A1, xa1, Bc1);
        vf4 tc0 = pk4_fma(A0, xc0, Bc0);
        vf4 tc1 = pk4_fma(A1, xc1, Bc1);

        vf4 ea0, ea1, ec0, ec1;
        ea0.x = __builtin_amdgcn_exp2f(ta0.x);
        ea0.y = __builtin_amdgcn_exp2f(ta0.y);
        ea0.z = __builtin_amdgcn_exp2f(ta0.z);
        ea0.w = __builtin_amdgcn_exp2f(ta0.w);
        ea1.x = __builtin_amdgcn_exp2f(ta1.x);
        ea1.y = __builtin_amdgcn_exp2f(ta1.y);
        ea1.z = __builtin_amdgcn_exp2f(ta1.z);
        ea1.w = __builtin_amdgcn_exp2f(ta1.w);
        ec0.x = __builtin_amdgcn_exp2f(tc0.x);
        ec0.y = __builtin_amdgcn_exp2f(tc0.y);
        ec0.z = __builtin_amdgcn_exp2f(tc0.z);
        ec0.w = __builtin_amdgcn_exp2f(tc0.w);
        ec1.x = __builtin_amdgcn_exp2f(tc1.x);
        ec1.y = __builtin_amdgcn_exp2f(tc1.y);
        ec1.z = __builtin_amdgcn_exp2f(tc1.z);
        ec1.w = __builtin_amdgcn_exp2f(tc1.w);

        // scaled numerator / denominator factors (scale on first elem only)
        vf4 na0 = pk4_fma(M0, ea0, Klo);
        vf4 na1 = pk4_fma(M1, ea1, One);
        vf4 da0 = pk4_fma(ea0, Klo, Klo);
        vf4 da1 = pk4_add(ea1, One);
        vf4 nc0 = pk4_fma(M0, ec0, Klo);
        vf4 nc1 = pk4_fma(M1, ec1, One);
        vf4 dc0 = pk4_fma(ec0, Klo, Klo);
        vf4 dc1 = pk4_add(ec1, One);

        // in-lane 8-way product trees (packed)
        vf4 qn_a = pk4_mul(na0, na1);
        vf4 qd_a = pk4_mul(da0, da1);
        vf4 qn_c = pk4_mul(nc0, nc1);
        vf4 qd_c = pk4_mul(dc0, dc1);
        vf2 hn_a = pk_mul(qn_a.lo, qn_a.hi);
        vf2 hd_a = pk_mul(qd_a.lo, qd_a.hi);
        vf2 hn_c = pk_mul(qn_c.lo, qn_c.hi);
        vf2 hd_c = pk_mul(qd_c.lo, qd_c.hi);
        float npA = hn_a.x * hn_a.y;
        float dpA = hd_a.x * hd_a.y;
        float npC = hn_c.x * hn_c.y;
        float dpC = hd_c.x * hd_c.y;

        // one rcp serves both batches: r_b = np_b / dp_b
        float inv = __builtin_amdgcn_rcpf(dpA * dpC);
        float rA  = npA * (dpC * inv);
        float rC  = npC * (dpA * inv);
        rbuf[wave][4 * q + p][col]     = rA;
        rbuf[wave][4 * q + 2 + p][col] = rC;
    }

    // ---- end-phase: per-batch product over the 32 ratio columns ----
    __syncthreads();

    if (lane < 32) {
        #pragma unroll
        for (int h2 = 0; h2 < 2; h2++) {           // rows lane, lane+32
            const int row = lane + 32 * h2;
            const float* rb2 = &rbuf[wave][row][0];
            vf4 a0 = *(const vf4*)(rb2)      * *(const vf4*)(rb2 + 4);
            vf4 a1 = *(const vf4*)(rb2 + 8)  * *(const vf4*)(rb2 + 12);
            vf4 a2 = *(const vf4*)(rb2 + 16) * *(const vf4*)(rb2 + 20);
            vf4 a3 = *(const vf4*)(rb2 + 24) * *(const vf4*)(rb2 + 28);
            vf4 m  = (a0 * a1) * (a2 * a3);
            vf2 h  = m.lo * m.hi;
            float z = h.x * h.y;                 // z(b0+row, r0)
            wz[wave][row] = head_w[r0] * z;
        }
    }
    __syncthreads();

    if (wave == 0) {                       // all 64 lanes: one batch each
        float s = (wz[0][lane] + wz[1][lane]) + (wz[2][lane] + wz[3][lane]);
        float t2 = (wz[4][lane] + wz[5][lane]) + (wz[6][lane] + wz[7][lane]);
        s += t2;
        if (blockIdx.x == 0) s += head_b[0];   // bias exactly once per batch
        atomicAdd(&y[b0 + lane], s);
    }
}

extern "C" void kernel_launch(void* const* d_in, const int* in_sizes, int n_in,
                              void* d_out, int out_size, void* d_ws, size_t ws_size,
                              hipStream_t stream) {
    const float* x  = (const float*)d_in[0];
    const float* th = (const float*)d_in[1];
    const float* sp = (const float*)d_in[2];
    const float* ml = (const float*)d_in[3];
    const float* lk = (const float*)d_in[4];
    const float* hw = (const float*)d_in[5];
    const float* hb = (const float*)d_in[6];
    float* y = (float*)d_out;

    float* pp = (float*)d_ws;   // 3 * 512 * 256 floats = 1.5 MB

    prep_kernel<<<R_TOT, 256, 0, stream>>>(th, sp, ml, lk, pp, y);
    dim3 grid(R_TOT / 8, B_TOT / 64, 1);
    main_kernel<<<grid, 512, 0, stream>>>(x, pp, hw, hb, y);
}

// Round 9
// 107.026 us; speedup vs baseline: 1.0503x; 1.0503x over previous
//
#include <hip/hip_runtime.h>
#include <math.h>

#define B_TOT 2048
#define R_TOT 512
#define D_TOT 256
#define LOG2E 1.4426950408889634f
#define SCALE_C 2.220446049250313e-16f   // 2^-52 exact

typedef float vf4 __attribute__((ext_vector_type(4)));
typedef float vf2 __attribute__((ext_vector_type(2)));

// gated = (1 + m1*e)/(1 + e),  e = exp2(A*x + Bc)
// A = -log2e*kappa*tanh(sign), Bc = -A*th, m1 = 1 - sigmoid(mask)
// Param planes: ppA[r*256+d], ppB[r*256+d], ppM[r*256+d].
// ppM carries 2^-52 folded at d%8==0 so each 8-d rcp group's num/den both
// carry the same scale -> ratio exact.
// Also zeroes y (blocks 0..7) so the separate memset dispatch is dropped.

__global__ void prep_kernel(const float* __restrict__ th,
                            const float* __restrict__ sp,
                            const float* __restrict__ ml,
                            const float* __restrict__ lk,
                            float* __restrict__ pp,
                            float* __restrict__ y) {
    int idx = blockIdx.x * 256 + threadIdx.x;   // r*256 + d
    if (blockIdx.x < (B_TOT / 256)) y[idx] = 0.0f;   // idx < 2048 here
    if (idx >= R_TOT * D_TOT) return;
    float kmul = -LOG2E * __builtin_amdgcn_exp2f(lk[0] * LOG2E);
    float u  = sp[idx];
    float eu = __builtin_amdgcn_exp2f(2.0f * LOG2E * u);
    float t  = 1.0f - 2.0f * __builtin_amdgcn_rcpf(eu + 1.0f);
    float A  = kmul * t;
    float Bc = -A * th[idx];
    float em = __builtin_amdgcn_exp2f(LOG2E * ml[idx]);
    float m1 = __builtin_amdgcn_rcpf(1.0f + em);
    int d = idx & 255;
    pp[idx]                       = A;
    pp[R_TOT * D_TOT + idx]       = Bc;
    pp[2 * R_TOT * D_TOT + idx]   = m1 * (((d & 7) == 0) ? SCALE_C : 1.0f);
}

// One rule's q-iter body (identical op sequence to round 6 -> bit-identical
// results). Returns the two 8-d scaled ratios for batch rows "A" and "C".
struct R2 { float rA, rC; };
static __device__ __forceinline__ R2 rule_body(
        vf4 A0, vf4 A1, vf4 Bc0, vf4 Bc1, vf4 M0, vf4 M1, vf4 Klo,
        vf4 xa0, vf4 xa1, vf4 xc0, vf4 xc1) {
    vf4 ta0 = A0 * xa0 + Bc0;          // v_pk_fma_f32 (r8: compiler packs)
    vf4 ta1 = A1 * xa1 + Bc1;
    vf4 tc0 = A0 * xc0 + Bc0;
    vf4 tc1 = A1 * xc1 + Bc1;

    vf4 ea0, ea1, ec0, ec1;
    ea0.x = __builtin_amdgcn_exp2f(ta0.x);
    ea0.y = __builtin_amdgcn_exp2f(ta0.y);
    ea0.z = __builtin_amdgcn_exp2f(ta0.z);
    ea0.w = __builtin_amdgcn_exp2f(ta0.w);
    ea1.x = __builtin_amdgcn_exp2f(ta1.x);
    ea1.y = __builtin_amdgcn_exp2f(ta1.y);
    ea1.z = __builtin_amdgcn_exp2f(ta1.z);
    ea1.w = __builtin_amdgcn_exp2f(ta1.w);
    ec0.x = __builtin_amdgcn_exp2f(tc0.x);
    ec0.y = __builtin_amdgcn_exp2f(tc0.y);
    ec0.z = __builtin_amdgcn_exp2f(tc0.z);
    ec0.w = __builtin_amdgcn_exp2f(tc0.w);
    ec1.x = __builtin_amdgcn_exp2f(tc1.x);
    ec1.y = __builtin_amdgcn_exp2f(tc1.y);
    ec1.z = __builtin_amdgcn_exp2f(tc1.z);
    ec1.w = __builtin_amdgcn_exp2f(tc1.w);

    // scaled numerator / denominator factors (scale on first elem only)
    vf4 na0 = M0 * ea0 + Klo;
    vf4 na1 = M1 * ea1 + 1.0f;
    vf4 da0 = ea0 * Klo + Klo;
    vf4 da1 = ea1 + 1.0f;
    vf4 nc0 = M0 * ec0 + Klo;
    vf4 nc1 = M1 * ec1 + 1.0f;
    vf4 dc0 = ec0 * Klo + Klo;
    vf4 dc1 = ec1 + 1.0f;

    // in-lane 8-way product trees
    vf4 qn_a = na0 * na1;
    vf4 qd_a = da0 * da1;
    vf4 qn_c = nc0 * nc1;
    vf4 qd_c = dc0 * dc1;
    vf2 hn_a = qn_a.lo * qn_a.hi;
    vf2 hd_a = qd_a.lo * qd_a.hi;
    vf2 hn_c = qn_c.lo * qn_c.hi;
    vf2 hd_c = qd_c.lo * qd_c.hi;
    float npA = hn_a.x * hn_a.y;
    float dpA = hd_a.x * hd_a.y;
    float npC = hn_c.x * hn_c.y;
    float dpC = hd_c.x * hd_c.y;

    // one rcp serves both batches: r_b = np_b / dp_b
    float inv = __builtin_amdgcn_rcpf(dpA * dpC);
    R2 out;
    out.rA = npA * (dpC * inv);
    out.rC = npC * (dpA * inv);
    return out;
}

// ---------------------------------------------------------------------------
// Main: WG = 256 = 4 waves. wave -> TWO rules (r0 = bx*8+wave, r1 = r0+4);
// block -> 8 rules x 32 batches. Each q-iter loads the 4 x-vectors ONCE and
// feeds both rules' bodies: loads per rule-q-iter halve (L1 traffic /2) and
// the second rule's ~360 cyc of independent math hides the first's load
// latency — the ILP round-7's prefetch failed to create (compiler sank it).
// Straight-line, fully unrolled, plain C (r5: dynamic loops spill; r8: asm
// is cost-neutral and perturbs scheduling). One atomicAdd per (block,
// batch): 64 adds/address. LDS 37.9 KB, VGPR ~48 params + working set ->
// __launch_bounds__(256,4) caps at 128 = 4 waves/SIMD, 4 blocks/CU.
// grid = (512/8 rules, 2048/32 batches) = 64 x 64.
// ---------------------------------------------------------------------------
__global__ __launch_bounds__(256, 4) void main_kernel(
        const float* __restrict__ x,       // [B_TOT][D_TOT]
        const float* __restrict__ pp,      // 3 planes of [R_TOT][D_TOT]
        const float* __restrict__ head_w,  // [R_TOT]
        const float* __restrict__ head_b,  // [1]
        float*       __restrict__ y) {     // [B_TOT]
    __shared__ float rbuf[8][32][36];      // 36.9 KB; [rule slot][batch][pad]
    __shared__ float wz[8][32];

    const int tid  = threadIdx.x;
    const int lane = tid & 63;
    const int wave = tid >> 6;             // 0..3
    const int col  = lane & 31;            // which 8-d group
    const int p    = lane >> 5;            // batch parity within row pair
    const int rA0  = (blockIdx.x << 3) + wave;        // rule slot = wave
    const int rB0  = rA0 + 4;                         // rule slot = wave+4
    const int b0   = blockIdx.y << 5;                 // 32 batches

    // ---- params for BOTH rules: two vf4 per plane each, held in VGPRs ----
    const float* pa = pp + rA0 * D_TOT + (col << 3);
    vf4 Aa0  = *(const vf4*)(pa);
    vf4 Aa1  = *(const vf4*)(pa + 4);
    vf4 Ba0  = *(const vf4*)(pa + R_TOT * D_TOT);
    vf4 Ba1  = *(const vf4*)(pa + R_TOT * D_TOT + 4);
    vf4 Ma0  = *(const vf4*)(pa + 2 * R_TOT * D_TOT);    // .x carries 2^-52
    vf4 Ma1  = *(const vf4*)(pa + 2 * R_TOT * D_TOT + 4);
    const float* pb = pp + rB0 * D_TOT + (col << 3);
    vf4 Ab0  = *(const vf4*)(pb);
    vf4 Ab1  = *(const vf4*)(pb + 4);
    vf4 Bb0  = *(const vf4*)(pb + R_TOT * D_TOT);
    vf4 Bb1  = *(const vf4*)(pb + R_TOT * D_TOT + 4);
    vf4 Mb0  = *(const vf4*)(pb + 2 * R_TOT * D_TOT);
    vf4 Mb1  = *(const vf4*)(pb + 2 * R_TOT * D_TOT + 4);
    const vf4 Klo = {SCALE_C, 1.0f, 1.0f, 1.0f};

    const float* xb = x + (size_t)(b0 + p) * D_TOT + (col << 3);

    #pragma unroll
    for (int q = 0; q < 8; q++) {
        // batch rows 4q+p ("A") and 4q+2+p ("C") — loaded ONCE for 2 rules
        const float* xq = xb + q * (4 * D_TOT);
        vf4 xa0 = *(const vf4*)(xq);
        vf4 xa1 = *(const vf4*)(xq + 4);
        vf4 xc0 = *(const vf4*)(xq + 2 * D_TOT);
        vf4 xc1 = *(const vf4*)(xq + 2 * D_TOT + 4);

        R2 ra = rule_body(Aa0, Aa1, Ba0, Ba1, Ma0, Ma1, Klo,
                          xa0, xa1, xc0, xc1);
        R2 rb = rule_body(Ab0, Ab1, Bb0, Bb1, Mb0, Mb1, Klo,
                          xa0, xa1, xc0, xc1);

        rbuf[wave][4 * q + p][col]         = ra.rA;
        rbuf[wave][4 * q + 2 + p][col]     = ra.rC;
        rbuf[wave + 4][4 * q + p][col]     = rb.rA;
        rbuf[wave + 4][4 * q + 2 + p][col] = rb.rC;
    }

    // ---- end-phase: 256 threads -> one (rule slot, batch) each ----
    __syncthreads();

    {
        const int slot = tid >> 5;             // 0..7 -> rule bx*8 + slot
        const int bb   = tid & 31;
        const float* rb2 = &rbuf[slot][bb][0];
        vf4 a0 = *(const vf4*)(rb2)      * *(const vf4*)(rb2 + 4);
        vf4 a1 = *(const vf4*)(rb2 + 8)  * *(const vf4*)(rb2 + 12);
        vf4 a2 = *(const vf4*)(rb2 + 16) * *(const vf4*)(rb2 + 20);
        vf4 a3 = *(const vf4*)(rb2 + 24) * *(const vf4*)(rb2 + 28);
        vf4 m  = (a0 * a1) * (a2 * a3);
        vf2 h  = m.lo * m.hi;
        float z = h.x * h.y;                   // z(b0+bb, bx*8+slot)
        wz[slot][bb] = head_w[(blockIdx.x << 3) + slot] * z;
    }
    __syncthreads();

    if (wave == 0 && lane < 32) {
        float s  = (wz[0][lane] + wz[1][lane]) + (wz[2][lane] + wz[3][lane]);
        float t2 = (wz[4][lane] + wz[5][lane]) + (wz[6][lane] + wz[7][lane]);
        s += t2;
        if (blockIdx.x == 0) s += head_b[0];   // bias exactly once per batch
        atomicAdd(&y[b0 + lane], s);
    }
}

extern "C" void kernel_launch(void* const* d_in, const int* in_sizes, int n_in,
                              void* d_out, int out_size, void* d_ws, size_t ws_size,
                              hipStream_t stream) {
    const float* x  = (const float*)d_in[0];
    const float* th = (const float*)d_in[1];
    const float* sp = (const float*)d_in[2];
    const float* ml = (const float*)d_in[3];
    const float* lk = (const float*)d_in[4];
    const float* hw = (const float*)d_in[5];
    const float* hb = (const float*)d_in[6];
    float* y = (float*)d_out;

    float* pp = (float*)d_ws;   // 3 * 512 * 256 floats = 1.5 MB

    prep_kernel<<<R_TOT, 256, 0, stream>>>(th, sp, ml, lk, pp, y);
    dim3 grid(R_TOT / 8, B_TOT / 32, 1);
    main_kernel<<<grid, 256, 0, stream>>>(x, pp, hw, hb, y);
}